// Round 4
// baseline (159.540 us; speedup 1.0000x reference)
//
#include <hip/hip_runtime.h>
#include <hip/hip_fp16.h>
#include <math.h>

#define OUTS 7
#define NBIN 49
#define NCH 256
#define LDSW 1200        // fallback kernel: float2 elems per wave window

// Channels-last workspace offsets (elements, fp16 in main path)
#define O1 15564800ull                  // 60800*256
#define O2 19456000ull                  // O1 + 15200*256
#define O3 20428800ull                  // O2 + 3800*256
#define WS_FLOATS 20672000ull           // O3 + 950*256
#define WS_BYTES  (WS_FLOATS * 4ull)    // keep original threshold (we need half)

// ---------------- transpose: [C][H][W] fp32 -> [HW][C] fp16 (channels-last) ----------------
__global__ __launch_bounds__(256) void transpose_cl(
    const float* __restrict__ f0, const float* __restrict__ f1,
    const float* __restrict__ f2, const float* __restrict__ f3,
    __half* __restrict__ ws)
{
    const int bt = blockIdx.x;
    const int cb = blockIdx.y * 64;
    const float* src; __half* dst; int HW, t0;
    if (bt < 950)       { src = f0; dst = ws;      HW = 60800; t0 = bt; }
    else if (bt < 1188) { src = f1; dst = ws + O1; HW = 15200; t0 = bt - 950; }
    else if (bt < 1248) { src = f2; dst = ws + O2; HW = 3800;  t0 = bt - 1188; }
    else                { src = f3; dst = ws + O3; HW = 950;   t0 = bt - 1248; }
    const int hw0 = t0 * 64;

    __shared__ float tile[64][65];
    const int tx = threadIdx.x & 63;
    const int ty = threadIdx.x >> 6;    // 0..3

#pragma unroll
    for (int j = 0; j < 16; ++j) {
        const int c = cb + ty + 4 * j;
        const int hw = hw0 + tx;
        tile[ty + 4 * j][tx] = (hw < HW) ? src[(size_t)c * HW + hw] : 0.0f;
    }
    __syncthreads();

    // store half2 (channel pair) per thread: wave writes contiguous segments
    const int cp = threadIdx.x & 31;   // channel pair 0..31 within this 64-ch block
    const int hh = threadIdx.x >> 5;   // 0..7
#pragma unroll
    for (int j = 0; j < 8; ++j) {
        const int hl = hh + 8 * j;
        const int hw = hw0 + hl;
        if (hw < HW) {
            const __half2 h = __floats2half2_rn(tile[2 * cp][hl], tile[2 * cp + 1][hl]);
            *(__half2*)(dst + (size_t)hw * 256 + cb + 2 * cp) = h;
        }
    }
}

// ---------------- main: LDS axis tables + fp16 channel-quads ----------------
// grid (K, 2): block = one RoI x 128 channels; half-wave (32 lanes x 4 ch)
// covers all 128 channels, so each wave processes a bin PAIR (lo half = bin b,
// hi half = bin b+1). 8 waves x 4 iters cover bins 0..48.
__global__ __launch_bounds__(512) void roi_main(
    const __half* __restrict__ ws, const float* __restrict__ rois,
    float* __restrict__ out, int K)
{
    const int k = blockIdx.x;
    const int cbase = blockIdx.y * 128;
    const int tid = threadIdx.x;
    const int wid = tid >> 6;          // 0..7
    const int lane = tid & 63;

    const float rx1 = rois[0 * K + k];
    const float ry1 = rois[1 * K + k];
    const float rx2 = rois[2 * K + k];
    const float ry2 = rois[3 * K + k];

    const float sroi = sqrtf((rx2 - rx1 + 1.0f) * (ry2 - ry1 + 1.0f));
    int lv = (int)floorf(log2f(sroi / 56.0f + 1e-6f));
    lv = lv < 0 ? 0 : (lv > 3 ? 3 : lv);

    const __half* wb; int H, W; float sc;
    switch (lv) {
        case 0:  wb = ws;      H = 200; W = 304; sc = 0.25f;    break;
        case 1:  wb = ws + O1; H = 100; W = 152; sc = 0.125f;   break;
        case 2:  wb = ws + O2; H = 50;  W = 76;  sc = 0.0625f;  break;
        default: wb = ws + O3; H = 25;  W = 38;  sc = 0.03125f; break;
    }

    const float y1s = ry1 * sc;
    const float ystep = fmaxf(ry2 * sc - y1s, 1.0f) / (float)OUTS;
    const float x1s = rx1 * sc;
    const float xstep = fmaxf(rx2 * sc - x1s, 1.0f) / (float)OUTS;

    // Per-axis node tables: 14 samples -> (node0 off, node1 off, w0, w1); 0.5
    // folded per axis so tap weight = yw*xw carries the 0.25 sample average.
    __shared__ int2   syo[14];  __shared__ float2 syw[14];
    __shared__ int2   sxo[14];  __shared__ float2 sxw[14];
    __shared__ __align__(16) float obuf[128 * NBIN];  // [channel][bin] == output layout

    if (tid < 14) {
        const int s = tid;
        const float g = ((float)s + 0.5f) * 0.5f;
        const float ysv = y1s + g * ystep;
        const float v = (ysv >= -1.0f && ysv <= (float)H) ? 0.5f : 0.0f;
        const float y = fminf(fmaxf(ysv, 0.0f), (float)(H - 1));
        const float yf = floorf(y);
        const int y0 = (int)yf;
        const float wy = y - yf;
        syo[s] = make_int2(y0 * W, min(y0 + 1, H - 1) * W);
        syw[s] = make_float2((1.0f - wy) * v, wy * v);
    } else if (tid < 28) {
        const int s = tid - 14;
        const float g = ((float)s + 0.5f) * 0.5f;
        const float xsv = x1s + g * xstep;
        const float v = (xsv >= -1.0f && xsv <= (float)W) ? 0.5f : 0.0f;
        const float x = fminf(fmaxf(xsv, 0.0f), (float)(W - 1));
        const float xf = floorf(x);
        const int x0 = (int)xf;
        const float wx = x - xf;
        sxo[s] = make_int2(x0, min(x0 + 1, W - 1));
        sxw[s] = make_float2((1.0f - wx) * v, wx * v);
    }
    __syncthreads();

    const int half = lane >> 5;          // 0: lo bin of pair, 1: hi bin
    const int ch4 = (lane & 31) * 4;     // channel quad within the 128-ch block
    const __half* wbl = wb + cbase + ch4;

#pragma unroll
    for (int i = 0; i < 4; ++i) {
        const int bl = 2 * wid + 16 * i;          // wave-uniform lo bin
        if (bl > 48) break;
        const int b = bl + half;                  // this lane's bin (49 = masked)
        const int bc = b > 48 ? 48 : b;           // clamped for table access
        const int oh = bc / OUTS;
        const int ow = bc - oh * OUTS;

        const int2   ya = syo[2 * oh], yb = syo[2 * oh + 1];
        const float2 wa = syw[2 * oh], wbv = syw[2 * oh + 1];
        const int2   xa = sxo[2 * ow], xb = sxo[2 * ow + 1];
        const float2 ua = sxw[2 * ow], ub = sxw[2 * ow + 1];

        const int   yo[4] = { ya.x, ya.y, yb.x, yb.y };
        const float yw[4] = { wa.x, wa.y, wbv.x, wbv.y };
        const int   xo[4] = { xa.x, xa.y, xb.x, xb.y };
        const float xw[4] = { ua.x, ua.y, ub.x, ub.y };

        float a0 = 0.0f, a1 = 0.0f, a2 = 0.0f, a3 = 0.0f;
#pragma unroll
        for (int iy = 0; iy < 4; ++iy) {
#pragma unroll
            for (int ix = 0; ix < 4; ++ix) {
                const uint2 h2 = *(const uint2*)(wbl + ((size_t)(yo[iy] + xo[ix]) << 8));
                const float2 v0 = __half22float2(*(const __half2*)&h2.x);
                const float2 v1 = __half22float2(*(const __half2*)&h2.y);
                const float wv = yw[iy] * xw[ix];
                a0 += v0.x * wv;
                a1 += v0.y * wv;
                a2 += v1.x * wv;
                a3 += v1.y * wv;
            }
        }
        if (b < NBIN) {
            obuf[(ch4 + 0) * NBIN + b] = a0;
            obuf[(ch4 + 1) * NBIN + b] = a1;
            obuf[(ch4 + 2) * NBIN + b] = a2;
            obuf[(ch4 + 3) * NBIN + b] = a3;
        }
    }
    __syncthreads();

    // obuf layout == output layout: straight contiguous float4 copy
    const float4* o4 = (const float4*)obuf;
    float4* d4 = (float4*)(out + ((size_t)k * NCH + cbase) * NBIN);
    for (int i = tid; i < (128 * NBIN) / 4; i += 512) d4[i] = o4[i];
}

// ---------------- fallback (Round-5 kernel) if ws too small ----------------
__global__ __launch_bounds__(256) void roi_extract_fallback(
    const float* __restrict__ f0, const float* __restrict__ f1,
    const float* __restrict__ f2, const float* __restrict__ f3,
    const float* __restrict__ rois, float* __restrict__ out, int K)
{
    const int k = blockIdx.x;
    if (k >= K) return;
    const int cbase = blockIdx.y * 32;
    const int tid = threadIdx.x;
    const int wid = tid >> 6;
    const int lane = tid & 63;
    const int bin = lane < NBIN ? lane : NBIN - 1;

    const float rx1 = rois[0 * K + k];
    const float ry1 = rois[1 * K + k];
    const float rx2 = rois[2 * K + k];
    const float ry2 = rois[3 * K + k];

    const float sroi = sqrtf((rx2 - rx1 + 1.0f) * (ry2 - ry1 + 1.0f));
    int lv = (int)floorf(log2f(sroi / 56.0f + 1e-6f));
    lv = lv < 0 ? 0 : (lv > 3 ? 3 : lv);

    const float* fbase; int H, W; float sc;
    switch (lv) {
        case 0:  fbase = f0; H = 200; W = 304; sc = 0.25f;    break;
        case 1:  fbase = f1; H = 100; W = 152; sc = 0.125f;   break;
        case 2:  fbase = f2; H = 50;  W = 76;  sc = 0.0625f;  break;
        default: fbase = f3; H = 25;  W = 38;  sc = 0.03125f; break;
    }
    const int HW = H * W;

    const float y1s = ry1 * sc;
    const float roih = fmaxf(ry2 * sc - y1s, 1.0f);
    const float x1s = rx1 * sc;
    const float roiw = fmaxf(rx2 * sc - x1s, 1.0f);
    const float ystep = roih / (float)OUTS;
    const float xstep = roiw / (float)OUTS;

    const float ysA = y1s + 0.25f * ystep, ysZ = y1s + 6.75f * ystep;
    const float xsA = x1s + 0.25f * xstep, xsZ = x1s + 6.75f * xstep;
    const int ylo = (int)floorf(fminf(fmaxf(ysA, 0.0f), (float)(H - 1)));
    const int xlo = (int)floorf(fminf(fmaxf(xsA, 0.0f), (float)(W - 1)));
    const int xhi = min((int)floorf(fminf(fmaxf(xsZ, 0.0f), (float)(W - 1))) + 1, W - 1);
    const int yhi = min((int)floorf(fminf(fmaxf(ysZ, 0.0f), (float)(H - 1))) + 1, H - 1);
    const int Ww = xhi - xlo + 1;
    const int Hw = yhi - ylo + 1;
    const int E = Ww * Hw;
    const bool useLds = (E <= LDSW);
    const int stride = useLds ? Ww : W;
    const int obase  = useLds ? 0 : (ylo * W + xlo);

    const int oh = bin / OUTS;
    const int ow = bin - oh * OUTS;

    int ry0[2], ry1i[2]; float wy[2], vy[2];
#pragma unroll
    for (int py = 0; py < 2; ++py) {
        const float g = ((float)(oh * 2 + py) + 0.5f) * 0.5f;
        const float ys = y1s + g * ystep;
        vy[py] = (ys >= -1.0f && ys <= (float)H) ? 1.0f : 0.0f;
        const float y = fminf(fmaxf(ys, 0.0f), (float)(H - 1));
        const float y0f = floorf(y);
        const int y0 = (int)y0f;
        ry0[py]  = y0 - ylo;
        ry1i[py] = min(y0 + 1, H - 1) - ylo;
        wy[py] = y - y0f;
    }
    int rx0[2], rx1i[2]; float wx[2], vx[2];
#pragma unroll
    for (int px = 0; px < 2; ++px) {
        const float g = ((float)(ow * 2 + px) + 0.5f) * 0.5f;
        const float xs = x1s + g * xstep;
        vx[px] = (xs >= -1.0f && xs <= (float)W) ? 1.0f : 0.0f;
        const float x = fminf(fmaxf(xs, 0.0f), (float)(W - 1));
        const float x0f = floorf(x);
        const int x0 = (int)x0f;
        rx0[px]  = x0 - xlo;
        rx1i[px] = min(x0 + 1, W - 1) - xlo;
        wx[px] = x - x0f;
    }

    int off[16]; float wt[16];
#pragma unroll
    for (int py = 0; py < 2; ++py) {
#pragma unroll
        for (int px = 0; px < 2; ++px) {
            const int i = (py * 2 + px) * 4;
            const float v = vy[py] * vx[px] * 0.25f;
            const float a = wy[py], b = wx[px];
            off[i + 0] = ry0[py]  * stride + rx0[px]  + obase; wt[i + 0] = (1.0f - a) * (1.0f - b) * v;
            off[i + 1] = ry0[py]  * stride + rx1i[px] + obase; wt[i + 1] = (1.0f - a) * b * v;
            off[i + 2] = ry1i[py] * stride + rx0[px]  + obase; wt[i + 2] = a * (1.0f - b) * v;
            off[i + 3] = ry1i[py] * stride + rx1i[px] + obase; wt[i + 3] = a * b * v;
        }
    }

    __shared__ float2 lds2[4 * LDSW];
    float2* const myw = &lds2[wid * LDSW];
    const float inv_Ww = 1.0f / (float)Ww;

#pragma unroll
    for (int j = 0; j < 4; ++j) {
        const int chA = cbase + wid * 8 + j * 2;
        const float* sA = fbase + (size_t)chA * HW + (size_t)ylo * W + xlo;
        const float* sB = sA + HW;

        if (useLds) {
            for (int e = lane; e < E; e += 64) {
                const int r = (int)(((float)e + 0.5f) * inv_Ww);
                const int g = r * W + (e - r * Ww);
                myw[e] = make_float2(sA[g], sB[g]);
            }
            if (lane < NBIN) {
                float ax = 0.0f, ay = 0.0f;
#pragma unroll
                for (int i = 0; i < 16; ++i) {
                    const float2 v = myw[off[i]];
                    ax += v.x * wt[i];
                    ay += v.y * wt[i];
                }
                float* outA = out + ((size_t)k * NCH + chA) * NBIN + bin;
                outA[0] = ax;
                outA[NBIN] = ay;
            }
        } else {
            if (lane < NBIN) {
                const float* pA = fbase + (size_t)chA * HW;
                const float* pB = pA + HW;
                float ax = 0.0f, ay = 0.0f;
#pragma unroll
                for (int i = 0; i < 16; ++i) {
                    ax += pA[off[i]] * wt[i];
                    ay += pB[off[i]] * wt[i];
                }
                float* outA = out + ((size_t)k * NCH + chA) * NBIN + bin;
                outA[0] = ax;
                outA[NBIN] = ay;
            }
        }
    }
}

extern "C" void kernel_launch(void* const* d_in, const int* in_sizes, int n_in,
                              void* d_out, int out_size, void* d_ws, size_t ws_size,
                              hipStream_t stream) {
    const float* f0 = (const float*)d_in[0];
    const float* f1 = (const float*)d_in[1];
    const float* f2 = (const float*)d_in[2];
    const float* f3 = (const float*)d_in[3];
    const float* rois = (const float*)d_in[4];
    float* out = (float*)d_out;
    int K = in_sizes[4] / 4;
    if (K <= 0) return;

    if (ws_size >= WS_BYTES) {
        __half* ws = (__half*)d_ws;
        transpose_cl<<<dim3(1263, 4), 256, 0, stream>>>(f0, f1, f2, f3, ws);
        roi_main<<<dim3(K, 2), 512, 0, stream>>>(ws, rois, out, K);
    } else {
        roi_extract_fallback<<<dim3(K, 8), 256, 0, stream>>>(f0, f1, f2, f3, rois, out, K);
    }
}

// Round 5
// 153.000 us; speedup vs baseline: 1.0427x; 1.0427x over previous
//
#include <hip/hip_runtime.h>
#include <hip/hip_fp16.h>
#include <math.h>

#define OUTS 7
#define NBIN 49
#define NCH 256
#define LDSW 1200        // fallback kernel: float2 elems per wave window

// Channels-last workspace offsets (elements, fp16 in main path)
#define O1 15564800ull                  // 60800*256
#define O2 19456000ull                  // O1 + 15200*256
#define O3 20428800ull                  // O2 + 3800*256
#define WS_FLOATS 20672000ull           // O3 + 950*256
#define WS_BYTES  (WS_FLOATS * 4ull)    // keep original threshold (we need half)

// ---------------- transpose: [C][H][W] fp32 -> [HW][C] fp16 (channels-last) ----------------
__global__ __launch_bounds__(256) void transpose_cl(
    const float* __restrict__ f0, const float* __restrict__ f1,
    const float* __restrict__ f2, const float* __restrict__ f3,
    __half* __restrict__ ws)
{
    const int bt = blockIdx.x;
    const int cb = blockIdx.y * 64;
    const float* src; __half* dst; int HW, t0;
    if (bt < 950)       { src = f0; dst = ws;      HW = 60800; t0 = bt; }
    else if (bt < 1188) { src = f1; dst = ws + O1; HW = 15200; t0 = bt - 950; }
    else if (bt < 1248) { src = f2; dst = ws + O2; HW = 3800;  t0 = bt - 1188; }
    else                { src = f3; dst = ws + O3; HW = 950;   t0 = bt - 1248; }
    const int hw0 = t0 * 64;

    __shared__ float tile[64][65];
    const int tx = threadIdx.x & 63;
    const int ty = threadIdx.x >> 6;    // 0..3

#pragma unroll
    for (int j = 0; j < 16; ++j) {
        const int c = cb + ty + 4 * j;
        const int hw = hw0 + tx;
        tile[ty + 4 * j][tx] = (hw < HW) ? src[(size_t)c * HW + hw] : 0.0f;
    }
    __syncthreads();

    // store half2 (channel pair) per thread: wave writes contiguous segments
    const int cp = threadIdx.x & 31;   // channel pair 0..31 within this 64-ch block
    const int hh = threadIdx.x >> 5;   // 0..7
#pragma unroll
    for (int j = 0; j < 8; ++j) {
        const int hl = hh + 8 * j;
        const int hw = hw0 + hl;
        if (hw < HW) {
            const __half2 h = __floats2half2_rn(tile[2 * cp][hl], tile[2 * cp + 1][hl]);
            *(__half2*)(dst + (size_t)hw * 256 + cb + 2 * cp) = h;
        }
    }
}

// ---------------- main: LDS axis tables + fp16 channel-pairs ----------------
// grid (K, 2): block = one RoI x 128 channels; lane = channel-pair (half2);
// 8 waves; each wave processes TWO wave-uniform bins per iteration
// (b0 = wid + 16i, b1 = b0 + 8) with all 32 tap loads issued before any
// accumulation -> 2x memory-level parallelism, zero divergence.
__global__ __launch_bounds__(512) void roi_main(
    const __half* __restrict__ ws, const float* __restrict__ rois,
    float* __restrict__ out, int K)
{
    const int k = blockIdx.x;
    const int cbase = blockIdx.y * 128;
    const int tid = threadIdx.x;
    const int wid = tid >> 6;          // 0..7
    const int lane = tid & 63;

    const float rx1 = rois[0 * K + k];
    const float ry1 = rois[1 * K + k];
    const float rx2 = rois[2 * K + k];
    const float ry2 = rois[3 * K + k];

    const float sroi = sqrtf((rx2 - rx1 + 1.0f) * (ry2 - ry1 + 1.0f));
    int lv = (int)floorf(log2f(sroi / 56.0f + 1e-6f));
    lv = lv < 0 ? 0 : (lv > 3 ? 3 : lv);

    const __half* wb; int H, W; float sc;
    switch (lv) {
        case 0:  wb = ws;      H = 200; W = 304; sc = 0.25f;    break;
        case 1:  wb = ws + O1; H = 100; W = 152; sc = 0.125f;   break;
        case 2:  wb = ws + O2; H = 50;  W = 76;  sc = 0.0625f;  break;
        default: wb = ws + O3; H = 25;  W = 38;  sc = 0.03125f; break;
    }

    const float y1s = ry1 * sc;
    const float ystep = fmaxf(ry2 * sc - y1s, 1.0f) / (float)OUTS;
    const float x1s = rx1 * sc;
    const float xstep = fmaxf(rx2 * sc - x1s, 1.0f) / (float)OUTS;

    // Per-axis node tables: 14 samples -> (node0 off, node1 off, w0, w1); 0.5
    // folded per axis so tap weight = yw*xw carries the 0.25 sample average.
    __shared__ int2   syo[14];  __shared__ float2 syw[14];
    __shared__ int2   sxo[14];  __shared__ float2 sxw[14];
    __shared__ __align__(16) float obuf[128 * NBIN];  // [channel][bin] == output layout

    if (tid < 14) {
        const int s = tid;
        const float g = ((float)s + 0.5f) * 0.5f;
        const float ysv = y1s + g * ystep;
        const float v = (ysv >= -1.0f && ysv <= (float)H) ? 0.5f : 0.0f;
        const float y = fminf(fmaxf(ysv, 0.0f), (float)(H - 1));
        const float yf = floorf(y);
        const int y0 = (int)yf;
        const float wy = y - yf;
        syo[s] = make_int2(y0 * W, min(y0 + 1, H - 1) * W);
        syw[s] = make_float2((1.0f - wy) * v, wy * v);
    } else if (tid < 28) {
        const int s = tid - 14;
        const float g = ((float)s + 0.5f) * 0.5f;
        const float xsv = x1s + g * xstep;
        const float v = (xsv >= -1.0f && xsv <= (float)W) ? 0.5f : 0.0f;
        const float x = fminf(fmaxf(xsv, 0.0f), (float)(W - 1));
        const float xf = floorf(x);
        const int x0 = (int)xf;
        const float wx = x - xf;
        sxo[s] = make_int2(x0, min(x0 + 1, W - 1));
        sxw[s] = make_float2((1.0f - wx) * v, wx * v);
    }
    __syncthreads();

    const __half* wbl = wb + cbase + 2 * lane;   // lane = channel pair

    for (int b0 = wid; b0 < NBIN; b0 += 16) {
        const bool two = (b0 + 8) < NBIN;        // wave-uniform
        const int b1 = two ? b0 + 8 : b0;        // clamp: duplicate loads, L1 hits

        int yoA[4]; float ywA[4]; int xoA[4]; float xwA[4];
        int yoB[4]; float ywB[4]; int xoB[4]; float xwB[4];
        {
            const int oh = b0 / OUTS;
            const int ow = b0 - oh * OUTS;
            const int2   ya = syo[2 * oh], yb = syo[2 * oh + 1];
            const float2 wa = syw[2 * oh], wv2 = syw[2 * oh + 1];
            const int2   xa = sxo[2 * ow], xb = sxo[2 * ow + 1];
            const float2 ua = sxw[2 * ow], ub = sxw[2 * ow + 1];
            yoA[0] = ya.x; yoA[1] = ya.y; yoA[2] = yb.x; yoA[3] = yb.y;
            ywA[0] = wa.x; ywA[1] = wa.y; ywA[2] = wv2.x; ywA[3] = wv2.y;
            xoA[0] = xa.x; xoA[1] = xa.y; xoA[2] = xb.x; xoA[3] = xb.y;
            xwA[0] = ua.x; xwA[1] = ua.y; xwA[2] = ub.x; xwA[3] = ub.y;
        }
        {
            const int oh = b1 / OUTS;
            const int ow = b1 - oh * OUTS;
            const int2   ya = syo[2 * oh], yb = syo[2 * oh + 1];
            const float2 wa = syw[2 * oh], wv2 = syw[2 * oh + 1];
            const int2   xa = sxo[2 * ow], xb = sxo[2 * ow + 1];
            const float2 ua = sxw[2 * ow], ub = sxw[2 * ow + 1];
            yoB[0] = ya.x; yoB[1] = ya.y; yoB[2] = yb.x; yoB[3] = yb.y;
            ywB[0] = wa.x; ywB[1] = wa.y; ywB[2] = wv2.x; ywB[3] = wv2.y;
            xoB[0] = xa.x; xoB[1] = xa.y; xoB[2] = xb.x; xoB[3] = xb.y;
            xwB[0] = ua.x; xwB[1] = ua.y; xwB[2] = ub.x; xwB[3] = ub.y;
        }

        // issue all 32 independent tap loads first (2x MLP)
        __half2 tA[16], tB[16];
#pragma unroll
        for (int iy = 0; iy < 4; ++iy) {
#pragma unroll
            for (int ix = 0; ix < 4; ++ix) {
                tA[iy * 4 + ix] = *(const __half2*)(wbl + ((size_t)(yoA[iy] + xoA[ix]) << 8));
                tB[iy * 4 + ix] = *(const __half2*)(wbl + ((size_t)(yoB[iy] + xoB[ix]) << 8));
            }
        }

        float a0 = 0.0f, a1 = 0.0f, c0 = 0.0f, c1 = 0.0f;
#pragma unroll
        for (int iy = 0; iy < 4; ++iy) {
#pragma unroll
            for (int ix = 0; ix < 4; ++ix) {
                const float2 vA = __half22float2(tA[iy * 4 + ix]);
                const float wvA = ywA[iy] * xwA[ix];
                a0 += vA.x * wvA;
                a1 += vA.y * wvA;
                const float2 vB = __half22float2(tB[iy * 4 + ix]);
                const float wvB = ywB[iy] * xwB[ix];
                c0 += vB.x * wvB;
                c1 += vB.y * wvB;
            }
        }
        obuf[(2 * lane) * NBIN + b0]     = a0;   // bank stride 2 -> free 2-way
        obuf[(2 * lane + 1) * NBIN + b0] = a1;
        if (two) {
            obuf[(2 * lane) * NBIN + b1]     = c0;
            obuf[(2 * lane + 1) * NBIN + b1] = c1;
        }
    }
    __syncthreads();

    // obuf layout == output layout: straight contiguous float4 copy
    const float4* o4 = (const float4*)obuf;
    float4* d4 = (float4*)(out + ((size_t)k * NCH + cbase) * NBIN);
    for (int i = tid; i < (128 * NBIN) / 4; i += 512) d4[i] = o4[i];
}

// ---------------- fallback (Round-5 kernel) if ws too small ----------------
__global__ __launch_bounds__(256) void roi_extract_fallback(
    const float* __restrict__ f0, const float* __restrict__ f1,
    const float* __restrict__ f2, const float* __restrict__ f3,
    const float* __restrict__ rois, float* __restrict__ out, int K)
{
    const int k = blockIdx.x;
    if (k >= K) return;
    const int cbase = blockIdx.y * 32;
    const int tid = threadIdx.x;
    const int wid = tid >> 6;
    const int lane = tid & 63;
    const int bin = lane < NBIN ? lane : NBIN - 1;

    const float rx1 = rois[0 * K + k];
    const float ry1 = rois[1 * K + k];
    const float rx2 = rois[2 * K + k];
    const float ry2 = rois[3 * K + k];

    const float sroi = sqrtf((rx2 - rx1 + 1.0f) * (ry2 - ry1 + 1.0f));
    int lv = (int)floorf(log2f(sroi / 56.0f + 1e-6f));
    lv = lv < 0 ? 0 : (lv > 3 ? 3 : lv);

    const float* fbase; int H, W; float sc;
    switch (lv) {
        case 0:  fbase = f0; H = 200; W = 304; sc = 0.25f;    break;
        case 1:  fbase = f1; H = 100; W = 152; sc = 0.125f;   break;
        case 2:  fbase = f2; H = 50;  W = 76;  sc = 0.0625f;  break;
        default: fbase = f3; H = 25;  W = 38;  sc = 0.03125f; break;
    }
    const int HW = H * W;

    const float y1s = ry1 * sc;
    const float roih = fmaxf(ry2 * sc - y1s, 1.0f);
    const float x1s = rx1 * sc;
    const float roiw = fmaxf(rx2 * sc - x1s, 1.0f);
    const float ystep = roih / (float)OUTS;
    const float xstep = roiw / (float)OUTS;

    const float ysA = y1s + 0.25f * ystep, ysZ = y1s + 6.75f * ystep;
    const float xsA = x1s + 0.25f * xstep, xsZ = x1s + 6.75f * xstep;
    const int ylo = (int)floorf(fminf(fmaxf(ysA, 0.0f), (float)(H - 1)));
    const int xlo = (int)floorf(fminf(fmaxf(xsA, 0.0f), (float)(W - 1)));
    const int xhi = min((int)floorf(fminf(fmaxf(xsZ, 0.0f), (float)(W - 1))) + 1, W - 1);
    const int yhi = min((int)floorf(fminf(fmaxf(ysZ, 0.0f), (float)(H - 1))) + 1, H - 1);
    const int Ww = xhi - xlo + 1;
    const int Hw = yhi - ylo + 1;
    const int E = Ww * Hw;
    const bool useLds = (E <= LDSW);
    const int stride = useLds ? Ww : W;
    const int obase  = useLds ? 0 : (ylo * W + xlo);

    const int oh = bin / OUTS;
    const int ow = bin - oh * OUTS;

    int ry0[2], ry1i[2]; float wy[2], vy[2];
#pragma unroll
    for (int py = 0; py < 2; ++py) {
        const float g = ((float)(oh * 2 + py) + 0.5f) * 0.5f;
        const float ys = y1s + g * ystep;
        vy[py] = (ys >= -1.0f && ys <= (float)H) ? 1.0f : 0.0f;
        const float y = fminf(fmaxf(ys, 0.0f), (float)(H - 1));
        const float y0f = floorf(y);
        const int y0 = (int)y0f;
        ry0[py]  = y0 - ylo;
        ry1i[py] = min(y0 + 1, H - 1) - ylo;
        wy[py] = y - y0f;
    }
    int rx0[2], rx1i[2]; float wx[2], vx[2];
#pragma unroll
    for (int px = 0; px < 2; ++px) {
        const float g = ((float)(ow * 2 + px) + 0.5f) * 0.5f;
        const float xs = x1s + g * xstep;
        vx[px] = (xs >= -1.0f && xs <= (float)W) ? 1.0f : 0.0f;
        const float x = fminf(fmaxf(xs, 0.0f), (float)(W - 1));
        const float x0f = floorf(x);
        const int x0 = (int)x0f;
        rx0[px]  = x0 - xlo;
        rx1i[px] = min(x0 + 1, W - 1) - xlo;
        wx[px] = x - x0f;
    }

    int off[16]; float wt[16];
#pragma unroll
    for (int py = 0; py < 2; ++py) {
#pragma unroll
        for (int px = 0; px < 2; ++px) {
            const int i = (py * 2 + px) * 4;
            const float v = vy[py] * vx[px] * 0.25f;
            const float a = wy[py], b = wx[px];
            off[i + 0] = ry0[py]  * stride + rx0[px]  + obase; wt[i + 0] = (1.0f - a) * (1.0f - b) * v;
            off[i + 1] = ry0[py]  * stride + rx1i[px] + obase; wt[i + 1] = (1.0f - a) * b * v;
            off[i + 2] = ry1i[py] * stride + rx0[px]  + obase; wt[i + 2] = a * (1.0f - b) * v;
            off[i + 3] = ry1i[py] * stride + rx1i[px] + obase; wt[i + 3] = a * b * v;
        }
    }

    __shared__ float2 lds2[4 * LDSW];
    float2* const myw = &lds2[wid * LDSW];
    const float inv_Ww = 1.0f / (float)Ww;

#pragma unroll
    for (int j = 0; j < 4; ++j) {
        const int chA = cbase + wid * 8 + j * 2;
        const float* sA = fbase + (size_t)chA * HW + (size_t)ylo * W + xlo;
        const float* sB = sA + HW;

        if (useLds) {
            for (int e = lane; e < E; e += 64) {
                const int r = (int)(((float)e + 0.5f) * inv_Ww);
                const int g = r * W + (e - r * Ww);
                myw[e] = make_float2(sA[g], sB[g]);
            }
            if (lane < NBIN) {
                float ax = 0.0f, ay = 0.0f;
#pragma unroll
                for (int i = 0; i < 16; ++i) {
                    const float2 v = myw[off[i]];
                    ax += v.x * wt[i];
                    ay += v.y * wt[i];
                }
                float* outA = out + ((size_t)k * NCH + chA) * NBIN + bin;
                outA[0] = ax;
                outA[NBIN] = ay;
            }
        } else {
            if (lane < NBIN) {
                const float* pA = fbase + (size_t)chA * HW;
                const float* pB = pA + HW;
                float ax = 0.0f, ay = 0.0f;
#pragma unroll
                for (int i = 0; i < 16; ++i) {
                    ax += pA[off[i]] * wt[i];
                    ay += pB[off[i]] * wt[i];
                }
                float* outA = out + ((size_t)k * NCH + chA) * NBIN + bin;
                outA[0] = ax;
                outA[NBIN] = ay;
            }
        }
    }
}

extern "C" void kernel_launch(void* const* d_in, const int* in_sizes, int n_in,
                              void* d_out, int out_size, void* d_ws, size_t ws_size,
                              hipStream_t stream) {
    const float* f0 = (const float*)d_in[0];
    const float* f1 = (const float*)d_in[1];
    const float* f2 = (const float*)d_in[2];
    const float* f3 = (const float*)d_in[3];
    const float* rois = (const float*)d_in[4];
    float* out = (float*)d_out;
    int K = in_sizes[4] / 4;
    if (K <= 0) return;

    if (ws_size >= WS_BYTES) {
        __half* ws = (__half*)d_ws;
        transpose_cl<<<dim3(1263, 4), 256, 0, stream>>>(f0, f1, f2, f3, ws);
        roi_main<<<dim3(K, 2), 512, 0, stream>>>(ws, rois, out, K);
    } else {
        roi_extract_fallback<<<dim3(K, 8), 256, 0, stream>>>(f0, f1, f2, f3, rois, out, K);
    }
}

// Round 6
// 151.516 us; speedup vs baseline: 1.0530x; 1.0098x over previous
//
#include <hip/hip_runtime.h>
#include <hip/hip_fp16.h>
#include <math.h>

#define OUTS 7
#define NBIN 49
#define NCH 256
#define LDSW 1200        // fallback kernel: float2 elems per wave window

// Channels-last workspace offsets (elements, fp16 in main path)
#define O1 15564800ull                  // 60800*256
#define O2 19456000ull                  // O1 + 15200*256
#define O3 20428800ull                  // O2 + 3800*256
#define WS_FLOATS 20672000ull           // O3 + 950*256
#define WS_BYTES  (WS_FLOATS * 4ull)    // keep original threshold (we need half)

// ---------------- transpose: [C][H][W] fp32 -> [HW][C] fp16 (channels-last) ----------------
// Vectorized: float4 loads (1KB/wave/instr), uint2 = 4ch fp16 stores (512B/wave/instr).
// Scalar fallback for tiles where HW%4!=0 (f3) or partial tiles.
__global__ __launch_bounds__(256) void transpose_cl(
    const float* __restrict__ f0, const float* __restrict__ f1,
    const float* __restrict__ f2, const float* __restrict__ f3,
    __half* __restrict__ ws)
{
    const int bt = blockIdx.x;
    const int cb = blockIdx.y * 64;
    const float* src; __half* dst; int HW, t0;
    if (bt < 950)       { src = f0; dst = ws;      HW = 60800; t0 = bt; }
    else if (bt < 1188) { src = f1; dst = ws + O1; HW = 15200; t0 = bt - 950; }
    else if (bt < 1248) { src = f2; dst = ws + O2; HW = 3800;  t0 = bt - 1188; }
    else                { src = f3; dst = ws + O3; HW = 950;   t0 = bt - 1248; }
    const int hw0 = t0 * 64;
    const int tid = threadIdx.x;

    __shared__ float tile[64][68];     // rows 16B-aligned (68*4 = 272B stride)

    const bool fast = ((HW & 3) == 0) && (hw0 + 64 <= HW);
    if (fast) {
        // 4 iters of float4: thread t -> channel (t>>4)+16j, hw quad (t&15)*4
#pragma unroll
        for (int j = 0; j < 4; ++j) {
            const int cl = (tid >> 4) + 16 * j;
            const int h4 = (tid & 15) * 4;
            const float4 v = *(const float4*)(src + (size_t)(cb + cl) * HW + hw0 + h4);
            *(float4*)&tile[cl][h4] = v;
        }
    } else {
        const int tx = tid & 63;
        const int ty = tid >> 6;    // 0..3
#pragma unroll
        for (int j = 0; j < 16; ++j) {
            const int c = cb + ty + 4 * j;
            const int hw = hw0 + tx;
            tile[ty + 4 * j][tx] = (hw < HW) ? src[(size_t)c * HW + hw] : 0.0f;
        }
    }
    __syncthreads();

    // store 4 fp16 channels per lane (uint2): 16 lanes cover one 128B row-chunk
#pragma unroll
    for (int j = 0; j < 4; ++j) {
        const int hl = (tid >> 4) + 16 * j;
        const int hw = hw0 + hl;
        if (hw < HW) {
            const int q = (tid & 15) * 4;
            const __half2 h0 = __floats2half2_rn(tile[q + 0][hl], tile[q + 1][hl]);
            const __half2 h1 = __floats2half2_rn(tile[q + 2][hl], tile[q + 3][hl]);
            uint2 u;
            u.x = *(const unsigned int*)&h0;
            u.y = *(const unsigned int*)&h1;
            *(uint2*)(dst + (size_t)hw * 256 + cb + q) = u;
        }
    }
}

// ---------------- main: LDS axis tables + fp16 channel-pairs ----------------
// grid (K, 2): block = one RoI x 128 channels; lane = channel-pair (half2);
// 8 waves; each wave processes TWO wave-uniform bins per iteration
// (b0 = wid + 16i, b1 = b0 + 8) with all 32 tap loads issued before any
// accumulation -> 2x memory-level parallelism, zero divergence.
__global__ __launch_bounds__(512) void roi_main(
    const __half* __restrict__ ws, const float* __restrict__ rois,
    float* __restrict__ out, int K)
{
    const int k = blockIdx.x;
    const int cbase = blockIdx.y * 128;
    const int tid = threadIdx.x;
    const int wid = tid >> 6;          // 0..7
    const int lane = tid & 63;

    const float rx1 = rois[0 * K + k];
    const float ry1 = rois[1 * K + k];
    const float rx2 = rois[2 * K + k];
    const float ry2 = rois[3 * K + k];

    const float sroi = sqrtf((rx2 - rx1 + 1.0f) * (ry2 - ry1 + 1.0f));
    int lv = (int)floorf(log2f(sroi / 56.0f + 1e-6f));
    lv = lv < 0 ? 0 : (lv > 3 ? 3 : lv);

    const __half* wb; int H, W; float sc;
    switch (lv) {
        case 0:  wb = ws;      H = 200; W = 304; sc = 0.25f;    break;
        case 1:  wb = ws + O1; H = 100; W = 152; sc = 0.125f;   break;
        case 2:  wb = ws + O2; H = 50;  W = 76;  sc = 0.0625f;  break;
        default: wb = ws + O3; H = 25;  W = 38;  sc = 0.03125f; break;
    }

    const float y1s = ry1 * sc;
    const float ystep = fmaxf(ry2 * sc - y1s, 1.0f) / (float)OUTS;
    const float x1s = rx1 * sc;
    const float xstep = fmaxf(rx2 * sc - x1s, 1.0f) / (float)OUTS;

    // Per-axis node tables: 14 samples -> (node0 off, node1 off, w0, w1); 0.5
    // folded per axis so tap weight = yw*xw carries the 0.25 sample average.
    __shared__ int2   syo[14];  __shared__ float2 syw[14];
    __shared__ int2   sxo[14];  __shared__ float2 sxw[14];
    __shared__ __align__(16) float obuf[128 * NBIN];  // [channel][bin] == output layout

    if (tid < 14) {
        const int s = tid;
        const float g = ((float)s + 0.5f) * 0.5f;
        const float ysv = y1s + g * ystep;
        const float v = (ysv >= -1.0f && ysv <= (float)H) ? 0.5f : 0.0f;
        const float y = fminf(fmaxf(ysv, 0.0f), (float)(H - 1));
        const float yf = floorf(y);
        const int y0 = (int)yf;
        const float wy = y - yf;
        syo[s] = make_int2(y0 * W, min(y0 + 1, H - 1) * W);
        syw[s] = make_float2((1.0f - wy) * v, wy * v);
    } else if (tid < 28) {
        const int s = tid - 14;
        const float g = ((float)s + 0.5f) * 0.5f;
        const float xsv = x1s + g * xstep;
        const float v = (xsv >= -1.0f && xsv <= (float)W) ? 0.5f : 0.0f;
        const float x = fminf(fmaxf(xsv, 0.0f), (float)(W - 1));
        const float xf = floorf(x);
        const int x0 = (int)xf;
        const float wx = x - xf;
        sxo[s] = make_int2(x0, min(x0 + 1, W - 1));
        sxw[s] = make_float2((1.0f - wx) * v, wx * v);
    }
    __syncthreads();

    const __half* wbl = wb + cbase + 2 * lane;   // lane = channel pair

    for (int b0 = wid; b0 < NBIN; b0 += 16) {
        const bool two = (b0 + 8) < NBIN;        // wave-uniform
        const int b1 = two ? b0 + 8 : b0;        // clamp: duplicate loads, L1 hits

        int yoA[4]; float ywA[4]; int xoA[4]; float xwA[4];
        int yoB[4]; float ywB[4]; int xoB[4]; float xwB[4];
        {
            const int oh = b0 / OUTS;
            const int ow = b0 - oh * OUTS;
            const int2   ya = syo[2 * oh], yb = syo[2 * oh + 1];
            const float2 wa = syw[2 * oh], wv2 = syw[2 * oh + 1];
            const int2   xa = sxo[2 * ow], xb = sxo[2 * ow + 1];
            const float2 ua = sxw[2 * ow], ub = sxw[2 * ow + 1];
            yoA[0] = ya.x; yoA[1] = ya.y; yoA[2] = yb.x; yoA[3] = yb.y;
            ywA[0] = wa.x; ywA[1] = wa.y; ywA[2] = wv2.x; ywA[3] = wv2.y;
            xoA[0] = xa.x; xoA[1] = xa.y; xoA[2] = xb.x; xoA[3] = xb.y;
            xwA[0] = ua.x; xwA[1] = ua.y; xwA[2] = ub.x; xwA[3] = ub.y;
        }
        {
            const int oh = b1 / OUTS;
            const int ow = b1 - oh * OUTS;
            const int2   ya = syo[2 * oh], yb = syo[2 * oh + 1];
            const float2 wa = syw[2 * oh], wv2 = syw[2 * oh + 1];
            const int2   xa = sxo[2 * ow], xb = sxo[2 * ow + 1];
            const float2 ua = sxw[2 * ow], ub = sxw[2 * ow + 1];
            yoB[0] = ya.x; yoB[1] = ya.y; yoB[2] = yb.x; yoB[3] = yb.y;
            ywB[0] = wa.x; ywB[1] = wa.y; ywB[2] = wv2.x; ywB[3] = wv2.y;
            xoB[0] = xa.x; xoB[1] = xa.y; xoB[2] = xb.x; xoB[3] = xb.y;
            xwB[0] = ua.x; xwB[1] = ua.y; xwB[2] = ub.x; xwB[3] = ub.y;
        }

        // issue all 32 independent tap loads first (2x MLP)
        __half2 tA[16], tB[16];
#pragma unroll
        for (int iy = 0; iy < 4; ++iy) {
#pragma unroll
            for (int ix = 0; ix < 4; ++ix) {
                tA[iy * 4 + ix] = *(const __half2*)(wbl + ((size_t)(yoA[iy] + xoA[ix]) << 8));
                tB[iy * 4 + ix] = *(const __half2*)(wbl + ((size_t)(yoB[iy] + xoB[ix]) << 8));
            }
        }

        float a0 = 0.0f, a1 = 0.0f, c0 = 0.0f, c1 = 0.0f;
#pragma unroll
        for (int iy = 0; iy < 4; ++iy) {
#pragma unroll
            for (int ix = 0; ix < 4; ++ix) {
                const float2 vA = __half22float2(tA[iy * 4 + ix]);
                const float wvA = ywA[iy] * xwA[ix];
                a0 += vA.x * wvA;
                a1 += vA.y * wvA;
                const float2 vB = __half22float2(tB[iy * 4 + ix]);
                const float wvB = ywB[iy] * xwB[ix];
                c0 += vB.x * wvB;
                c1 += vB.y * wvB;
            }
        }
        obuf[(2 * lane) * NBIN + b0]     = a0;   // bank stride 2 -> free 2-way
        obuf[(2 * lane + 1) * NBIN + b0] = a1;
        if (two) {
            obuf[(2 * lane) * NBIN + b1]     = c0;
            obuf[(2 * lane + 1) * NBIN + b1] = c1;
        }
    }
    __syncthreads();

    // obuf layout == output layout: straight contiguous float4 copy
    const float4* o4 = (const float4*)obuf;
    float4* d4 = (float4*)(out + ((size_t)k * NCH + cbase) * NBIN);
    for (int i = tid; i < (128 * NBIN) / 4; i += 512) d4[i] = o4[i];
}

// ---------------- fallback (Round-5 kernel) if ws too small ----------------
__global__ __launch_bounds__(256) void roi_extract_fallback(
    const float* __restrict__ f0, const float* __restrict__ f1,
    const float* __restrict__ f2, const float* __restrict__ f3,
    const float* __restrict__ rois, float* __restrict__ out, int K)
{
    const int k = blockIdx.x;
    if (k >= K) return;
    const int cbase = blockIdx.y * 32;
    const int tid = threadIdx.x;
    const int wid = tid >> 6;
    const int lane = tid & 63;
    const int bin = lane < NBIN ? lane : NBIN - 1;

    const float rx1 = rois[0 * K + k];
    const float ry1 = rois[1 * K + k];
    const float rx2 = rois[2 * K + k];
    const float ry2 = rois[3 * K + k];

    const float sroi = sqrtf((rx2 - rx1 + 1.0f) * (ry2 - ry1 + 1.0f));
    int lv = (int)floorf(log2f(sroi / 56.0f + 1e-6f));
    lv = lv < 0 ? 0 : (lv > 3 ? 3 : lv);

    const float* fbase; int H, W; float sc;
    switch (lv) {
        case 0:  fbase = f0; H = 200; W = 304; sc = 0.25f;    break;
        case 1:  fbase = f1; H = 100; W = 152; sc = 0.125f;   break;
        case 2:  fbase = f2; H = 50;  W = 76;  sc = 0.0625f;  break;
        default: fbase = f3; H = 25;  W = 38;  sc = 0.03125f; break;
    }
    const int HW = H * W;

    const float y1s = ry1 * sc;
    const float roih = fmaxf(ry2 * sc - y1s, 1.0f);
    const float x1s = rx1 * sc;
    const float roiw = fmaxf(rx2 * sc - x1s, 1.0f);
    const float ystep = roih / (float)OUTS;
    const float xstep = roiw / (float)OUTS;

    const float ysA = y1s + 0.25f * ystep, ysZ = y1s + 6.75f * ystep;
    const float xsA = x1s + 0.25f * xstep, xsZ = x1s + 6.75f * xstep;
    const int ylo = (int)floorf(fminf(fmaxf(ysA, 0.0f), (float)(H - 1)));
    const int xlo = (int)floorf(fminf(fmaxf(xsA, 0.0f), (float)(W - 1)));
    const int xhi = min((int)floorf(fminf(fmaxf(xsZ, 0.0f), (float)(W - 1))) + 1, W - 1);
    const int yhi = min((int)floorf(fminf(fmaxf(ysZ, 0.0f), (float)(H - 1))) + 1, H - 1);
    const int Ww = xhi - xlo + 1;
    const int Hw = yhi - ylo + 1;
    const int E = Ww * Hw;
    const bool useLds = (E <= LDSW);
    const int stride = useLds ? Ww : W;
    const int obase  = useLds ? 0 : (ylo * W + xlo);

    const int oh = bin / OUTS;
    const int ow = bin - oh * OUTS;

    int ry0[2], ry1i[2]; float wy[2], vy[2];
#pragma unroll
    for (int py = 0; py < 2; ++py) {
        const float g = ((float)(oh * 2 + py) + 0.5f) * 0.5f;
        const float ys = y1s + g * ystep;
        vy[py] = (ys >= -1.0f && ys <= (float)H) ? 1.0f : 0.0f;
        const float y = fminf(fmaxf(ys, 0.0f), (float)(H - 1));
        const float y0f = floorf(y);
        const int y0 = (int)y0f;
        ry0[py]  = y0 - ylo;
        ry1i[py] = min(y0 + 1, H - 1) - ylo;
        wy[py] = y - y0f;
    }
    int rx0[2], rx1i[2]; float wx[2], vx[2];
#pragma unroll
    for (int px = 0; px < 2; ++px) {
        const float g = ((float)(ow * 2 + px) + 0.5f) * 0.5f;
        const float xs = x1s + g * xstep;
        vx[px] = (xs >= -1.0f && xs <= (float)W) ? 1.0f : 0.0f;
        const float x = fminf(fmaxf(xs, 0.0f), (float)(W - 1));
        const float x0f = floorf(x);
        const int x0 = (int)x0f;
        rx0[px]  = x0 - xlo;
        rx1i[px] = min(x0 + 1, W - 1) - xlo;
        wx[px] = x - x0f;
    }

    int off[16]; float wt[16];
#pragma unroll
    for (int py = 0; py < 2; ++py) {
#pragma unroll
        for (int px = 0; px < 2; ++px) {
            const int i = (py * 2 + px) * 4;
            const float v = vy[py] * vx[px] * 0.25f;
            const float a = wy[py], b = wx[px];
            off[i + 0] = ry0[py]  * stride + rx0[px]  + obase; wt[i + 0] = (1.0f - a) * (1.0f - b) * v;
            off[i + 1] = ry0[py]  * stride + rx1i[px] + obase; wt[i + 1] = (1.0f - a) * b * v;
            off[i + 2] = ry1i[py] * stride + rx0[px]  + obase; wt[i + 2] = a * (1.0f - b) * v;
            off[i + 3] = ry1i[py] * stride + rx1i[px] + obase; wt[i + 3] = a * b * v;
        }
    }

    __shared__ float2 lds2[4 * LDSW];
    float2* const myw = &lds2[wid * LDSW];
    const float inv_Ww = 1.0f / (float)Ww;

#pragma unroll
    for (int j = 0; j < 4; ++j) {
        const int chA = cbase + wid * 8 + j * 2;
        const float* sA = fbase + (size_t)chA * HW + (size_t)ylo * W + xlo;
        const float* sB = sA + HW;

        if (useLds) {
            for (int e = lane; e < E; e += 64) {
                const int r = (int)(((float)e + 0.5f) * inv_Ww);
                const int g = r * W + (e - r * Ww);
                myw[e] = make_float2(sA[g], sB[g]);
            }
            if (lane < NBIN) {
                float ax = 0.0f, ay = 0.0f;
#pragma unroll
                for (int i = 0; i < 16; ++i) {
                    const float2 v = myw[off[i]];
                    ax += v.x * wt[i];
                    ay += v.y * wt[i];
                }
                float* outA = out + ((size_t)k * NCH + chA) * NBIN + bin;
                outA[0] = ax;
                outA[NBIN] = ay;
            }
        } else {
            if (lane < NBIN) {
                const float* pA = fbase + (size_t)chA * HW;
                const float* pB = pA + HW;
                float ax = 0.0f, ay = 0.0f;
#pragma unroll
                for (int i = 0; i < 16; ++i) {
                    ax += pA[off[i]] * wt[i];
                    ay += pB[off[i]] * wt[i];
                }
                float* outA = out + ((size_t)k * NCH + chA) * NBIN + bin;
                outA[0] = ax;
                outA[NBIN] = ay;
            }
        }
    }
}

extern "C" void kernel_launch(void* const* d_in, const int* in_sizes, int n_in,
                              void* d_out, int out_size, void* d_ws, size_t ws_size,
                              hipStream_t stream) {
    const float* f0 = (const float*)d_in[0];
    const float* f1 = (const float*)d_in[1];
    const float* f2 = (const float*)d_in[2];
    const float* f3 = (const float*)d_in[3];
    const float* rois = (const float*)d_in[4];
    float* out = (float*)d_out;
    int K = in_sizes[4] / 4;
    if (K <= 0) return;

    if (ws_size >= WS_BYTES) {
        __half* ws = (__half*)d_ws;
        transpose_cl<<<dim3(1263, 4), 256, 0, stream>>>(f0, f1, f2, f3, ws);
        roi_main<<<dim3(K, 2), 512, 0, stream>>>(ws, rois, out, K);
    } else {
        roi_extract_fallback<<<dim3(K, 8), 256, 0, stream>>>(f0, f1, f2, f3, rois, out, K);
    }
}